// Round 11
// baseline (211.682 us; speedup 1.0000x reference)
//
#include <hip/hip_runtime.h>

// LabelGenerator: masks [32,1,768,768] f32 in {0,1}
//  out0 = 35x35 box mean (SAME, zero pad)      -> f32 [32,768,768]
//  out1 = pfm: mask?1 : (31x31 dilation?0 : 2) -> f32 values 0/1/2
// R11: K0 pre-pass packs the mask to a 2.36 MB global bitmap (u64 segments);
// main kernel = R10 three-phase structure but phase A loads the bitmap
// (L2/LLC-resident, halo re-reads free) instead of 129 MB of f32 ->
// main kernel is nearly pure-write (151 MB). Net HBM 280 -> 232 MB and the
// serial read phase ahead of the barriers collapses.
// Dilation on a 0/1 mask == (31x31 box sum >= 1).

#define BATCH 32
#define HH 768
#define WW 768
#define NPIX (HH * WW)

constexpr int TYO  = 48;               // output rows per block
constexpr int HALO = 17;               // 35//2
constexpr int ROWS = TYO + 2 * HALO;   // 82 staged rows
constexpr int NSEG = 12;               // 768/64 u64 segments per row
constexpr int SSEG = NSEG + 2;         // +2 zero-pad segments
constexpr int NT   = 768;              // threads per block (12 waves)
constexpr int NG   = 4;                // row groups
constexpr int RPG  = TYO / NG;         // 12 output rows per group
constexpr int CT   = 192;              // col-threads per group (x4 cols)

typedef float v4f __attribute__((ext_vector_type(4)));

// ---------------- K0: f32 mask -> u64 bitmap (2.36 MB) ----------------
__global__ __launch_bounds__(256)
void packbits_kernel(const float* __restrict__ in,
                     unsigned long long* __restrict__ bits) {
    const int lane = threadIdx.x & 63;
    const int wv   = threadIdx.x >> 6;
    const size_t gr = (size_t)blockIdx.x * 4 + wv;   // global row 0..24575
    const float* rp = in + gr * WW;
    unsigned long long bb = 0;
    #pragma unroll
    for (int j = 0; j < NSEG; ++j) {
        const unsigned long long m = __ballot(rp[64 * j + lane] > 0.5f);
        if (lane == j) bb = m;        // lane j keeps segment j
    }
    if (lane < NSEG) bits[gr * NSEG + lane] = bb;
}

// ---------------- main: bitmap -> outputs (R10 structure) ----------------
__global__ __launch_bounds__(NT)
void label_gen_fused_bits(const unsigned long long* __restrict__ bits,
                          float* __restrict__ out) {
    __shared__ unsigned long long sbits[ROWS][SSEG];   // 9184 B
    __shared__ unsigned int hm[ROWS][CT];              // 62976 B packed bytes

    const int tid = threadIdx.x;
    const int y0  = blockIdx.x * TYO;
    const int b   = blockIdx.y;

    // ---- Phase A': global bitmap -> LDS bit rows (L2/LLC hits) ----
    for (int idx = tid; idx < ROWS * NSEG; idx += NT) {
        const int lr = idx / NSEG;
        const int j  = idx - lr * NSEG;
        const int r  = y0 - HALO + lr;
        unsigned long long v = 0ull;
        if ((unsigned)r < (unsigned)HH)
            v = bits[((size_t)b * HH + r) * NSEG + j];
        sbits[lr][j + 1] = v;
    }
    for (int lr = tid; lr < ROWS; lr += NT) {
        sbits[lr][0] = 0ull;
        sbits[lr][SSEG - 1] = 0ull;
    }
    __syncthreads();

    // ---- Phase H: per-row horizontal values, each row evaluated once ----
    {
        const int r0 = tid / CT;            // 0..3
        const int ct = tid - r0 * CT;       // 0..191
        const int c0 = 4 * ct;
        const int s  = c0 - HALO;
        const int q  = (s >> 6) + 1;        // padded u64 index (arith shift)
        const int sh = s & 63;              // odd -> never 0
        const unsigned long long M35 = (1ull << 35) - 1;
        for (int lr = r0; lr < ROWS; lr += NG) {
            // win bit j = mask col c0-17+j
            const unsigned long long w =
                (sbits[lr][q] >> sh) | (sbits[lr][q + 1] << (64 - sh));
            const int h0 = (int)__popcll(w & M35);
            const int h1 = h0 + (int)((w >> 35) & 1) - (int)(w & 1);
            const int h2 = h1 + (int)((w >> 36) & 1) - (int)((w >> 1) & 1);
            const int h3 = h2 + (int)((w >> 37) & 1) - (int)((w >> 2) & 1);
            // 16-smear: sm bit k = OR of w bits k..k+15
            unsigned long long sm = w | (w >> 1);
            sm |= sm >> 2; sm |= sm >> 4; sm |= sm >> 8;
            // or31 for col c0+j = OR of w bits (j+2)..(j+32) = sm[j+2]|sm[j+17]
            const unsigned int o4 = (unsigned int)(((sm >> 2) | (sm >> 17)) & 0xFull);
            const unsigned int m4 = (unsigned int)((w >> 17) & 0xFull);
            const unsigned int mb =
                (((m4 & 1u) | ((m4 & 2u) << 7) | ((m4 & 4u) << 14) | ((m4 & 8u) << 21)) << 6);
            const unsigned int ob =
                (((o4 & 1u) | ((o4 & 2u) << 7) | ((o4 & 4u) << 14) | ((o4 & 8u) << 21)) << 7);
            hm[lr][ct] = (unsigned)h0 | ((unsigned)h1 << 8) | ((unsigned)h2 << 16)
                       | ((unsigned)h3 << 24) | mb | ob;
        }
    }
    __syncthreads();

    // ---- Phase B: vertical SWAR sliding sums over packed bytes ----
    const int g   = tid / CT;           // 0..3
    const int ct  = tid - g * CT;       // 0..191
    const int c0  = 4 * ct;
    const int yb  = y0 + RPG * g;       // group's first output row
    const int lr0 = RPG * g;            // LDS row of image row yb-17

    const unsigned int M6 = 0x003F003Fu;   // 6-bit h fields of bytes (0,2)/(1,3)
    const unsigned int M1 = 0x01010101u;   // or-flag per byte

    unsigned int vA = 0, vB = 0;   // 2x16-bit fields: cols (0,2) and (1,3)
    unsigned int c31 = 0;          // 4x8-bit or-flag counts per col
    unsigned int ring_e[2], ring_l[2];
    #pragma unroll
    for (int k = 0; k < 35; ++k) {
        const unsigned int x = hm[lr0 + k][ct];
        vA += x & M6;
        vB += (x >> 8) & M6;
        if (k >= 2 && k <= 32) c31 += (x >> 7) & M1;
        if (k == 0)  ring_l[0] = x;    // row lr0+0 (l35 at i=0)
        if (k == 1)  ring_l[1] = x;    // row lr0+1 (l35 at i=1)
        if (k == 33) ring_e[0] = x;    // row lr0+33 (e31 at i=0)
        if (k == 34) ring_e[1] = x;    // row lr0+34 (e31 at i=1)
    }

    float* orow = out + (size_t)b * NPIX + (size_t)yb * WW + c0;
    float* prow = orow + (size_t)BATCH * NPIX;

    for (int i = 0; i < RPG; ++i) {
        const int lr = lr0 + HALO + i;         // LDS row of output row yb+i
        const unsigned int xc = hm[lr][ct];    // center row (mask bits)

        v4f r4, p4;
        r4.x = (float)(vA & 0xFFFFu) * (1.0f / 1225.0f);
        r4.y = (float)(vB & 0xFFFFu) * (1.0f / 1225.0f);
        r4.z = (float)(vA >> 16)     * (1.0f / 1225.0f);
        r4.w = (float)(vB >> 16)     * (1.0f / 1225.0f);
        p4.x = ((xc >> 6) & 1u)  ? 1.0f : ((c31 & 0xFFu)         ? 0.0f : 2.0f);
        p4.y = ((xc >> 14) & 1u) ? 1.0f : (((c31 >> 8) & 0xFFu)  ? 0.0f : 2.0f);
        p4.z = ((xc >> 22) & 1u) ? 1.0f : (((c31 >> 16) & 0xFFu) ? 0.0f : 2.0f);
        p4.w = ((xc >> 30) & 1u) ? 1.0f : ((c31 >> 24)           ? 0.0f : 2.0f);

        __builtin_nontemporal_store(r4, (v4f*)orow);   // bypass L2/LLC
        __builtin_nontemporal_store(p4, (v4f*)prow);
        orow += WW; prow += WW;

        if (i < RPG - 1) {
            const unsigned int xe   = hm[lr + 18][ct];      // e35 row lr0+35+i
            const unsigned int xl31 = hm[lr0 + 2 + i][ct];  // l31 row lr0+2+i
            const unsigned int xe31 = ring_e[i & 1];        // e31 row lr0+33+i
            const unsigned int xl   = ring_l[i & 1];        // l35 row lr0+i
            ring_e[i & 1] = xe;                             // reused at i+2
            ring_l[i & 1] = xl31;                           // reused at i+2
            // per-field: 0 <= value <= 1225+35 < 2^16 (and <=32 < 2^8) -> SWAR-safe
            vA  = (vA + (xe & M6)) - (xl & M6);
            vB  = (vB + ((xe >> 8) & M6)) - ((xl >> 8) & M6);
            c31 = (c31 + ((xe31 >> 7) & M1)) - ((xl31 >> 7) & M1);
        }
    }
}

// ---------------- Fallback: R10 fused single kernel (passing, 211.7) --------
__global__ __launch_bounds__(NT)
void label_gen_fused(const float* __restrict__ in, float* __restrict__ out) {
    __shared__ unsigned long long sbits[ROWS][SSEG];
    __shared__ unsigned int hm[ROWS][CT];

    const int tid  = threadIdx.x;
    const int lane = tid & 63;
    const int wv   = tid >> 6;
    const int y0   = blockIdx.x * TYO;
    const int b    = blockIdx.y;
    const float* __restrict__ src = in + (size_t)b * NPIX;

    for (int lr = wv; lr < ROWS; lr += NT / 64) {
        const int r = y0 - HALO + lr;
        unsigned long long bb[NSEG];
        if ((unsigned)r < (unsigned)HH) {
            const float* rp = src + (size_t)r * WW;
            #pragma unroll
            for (int j = 0; j < NSEG; ++j)
                bb[j] = __ballot(rp[64 * j + lane] > 0.5f);
        } else {
            #pragma unroll
            for (int j = 0; j < NSEG; ++j) bb[j] = 0ull;
        }
        if (lane == 0) {
            sbits[lr][0] = 0ull;
            #pragma unroll
            for (int j = 0; j < NSEG; ++j) sbits[lr][j + 1] = bb[j];
            sbits[lr][SSEG - 1] = 0ull;
        }
    }
    __syncthreads();

    {
        const int r0 = tid / CT;
        const int ct = tid - r0 * CT;
        const int c0 = 4 * ct;
        const int s  = c0 - HALO;
        const int q  = (s >> 6) + 1;
        const int sh = s & 63;
        const unsigned long long M35 = (1ull << 35) - 1;
        for (int lr = r0; lr < ROWS; lr += NG) {
            const unsigned long long w =
                (sbits[lr][q] >> sh) | (sbits[lr][q + 1] << (64 - sh));
            const int h0 = (int)__popcll(w & M35);
            const int h1 = h0 + (int)((w >> 35) & 1) - (int)(w & 1);
            const int h2 = h1 + (int)((w >> 36) & 1) - (int)((w >> 1) & 1);
            const int h3 = h2 + (int)((w >> 37) & 1) - (int)((w >> 2) & 1);
            unsigned long long sm = w | (w >> 1);
            sm |= sm >> 2; sm |= sm >> 4; sm |= sm >> 8;
            const unsigned int o4 = (unsigned int)(((sm >> 2) | (sm >> 17)) & 0xFull);
            const unsigned int m4 = (unsigned int)((w >> 17) & 0xFull);
            const unsigned int mb =
                (((m4 & 1u) | ((m4 & 2u) << 7) | ((m4 & 4u) << 14) | ((m4 & 8u) << 21)) << 6);
            const unsigned int ob =
                (((o4 & 1u) | ((o4 & 2u) << 7) | ((o4 & 4u) << 14) | ((o4 & 8u) << 21)) << 7);
            hm[lr][ct] = (unsigned)h0 | ((unsigned)h1 << 8) | ((unsigned)h2 << 16)
                       | ((unsigned)h3 << 24) | mb | ob;
        }
    }
    __syncthreads();

    const int g   = tid / CT;
    const int ct  = tid - g * CT;
    const int c0  = 4 * ct;
    const int yb  = y0 + RPG * g;
    const int lr0 = RPG * g;
    const unsigned int M6 = 0x003F003Fu;
    const unsigned int M1 = 0x01010101u;

    unsigned int vA = 0, vB = 0, c31 = 0;
    unsigned int ring_e[2], ring_l[2];
    #pragma unroll
    for (int k = 0; k < 35; ++k) {
        const unsigned int x = hm[lr0 + k][ct];
        vA += x & M6;
        vB += (x >> 8) & M6;
        if (k >= 2 && k <= 32) c31 += (x >> 7) & M1;
        if (k == 0)  ring_l[0] = x;
        if (k == 1)  ring_l[1] = x;
        if (k == 33) ring_e[0] = x;
        if (k == 34) ring_e[1] = x;
    }

    float* orow = out + (size_t)b * NPIX + (size_t)yb * WW + c0;
    float* prow = orow + (size_t)BATCH * NPIX;

    for (int i = 0; i < RPG; ++i) {
        const int lr = lr0 + HALO + i;
        const unsigned int xc = hm[lr][ct];
        v4f r4, p4;
        r4.x = (float)(vA & 0xFFFFu) * (1.0f / 1225.0f);
        r4.y = (float)(vB & 0xFFFFu) * (1.0f / 1225.0f);
        r4.z = (float)(vA >> 16)     * (1.0f / 1225.0f);
        r4.w = (float)(vB >> 16)     * (1.0f / 1225.0f);
        p4.x = ((xc >> 6) & 1u)  ? 1.0f : ((c31 & 0xFFu)         ? 0.0f : 2.0f);
        p4.y = ((xc >> 14) & 1u) ? 1.0f : (((c31 >> 8) & 0xFFu)  ? 0.0f : 2.0f);
        p4.z = ((xc >> 22) & 1u) ? 1.0f : (((c31 >> 16) & 0xFFu) ? 0.0f : 2.0f);
        p4.w = ((xc >> 30) & 1u) ? 1.0f : ((c31 >> 24)           ? 0.0f : 2.0f);
        __builtin_nontemporal_store(r4, (v4f*)orow);
        __builtin_nontemporal_store(p4, (v4f*)prow);
        orow += WW; prow += WW;
        if (i < RPG - 1) {
            const unsigned int xe   = hm[lr + 18][ct];
            const unsigned int xl31 = hm[lr0 + 2 + i][ct];
            const unsigned int xe31 = ring_e[i & 1];
            const unsigned int xl   = ring_l[i & 1];
            ring_e[i & 1] = xe;
            ring_l[i & 1] = xl31;
            vA  = (vA + (xe & M6)) - (xl & M6);
            vB  = (vB + ((xe >> 8) & M6)) - ((xl >> 8) & M6);
            c31 = (c31 + ((xe31 >> 7) & M1)) - ((xl31 >> 7) & M1);
        }
    }
}

extern "C" void kernel_launch(void* const* d_in, const int* in_sizes, int n_in,
                              void* d_out, int out_size, void* d_ws, size_t ws_size,
                              hipStream_t stream) {
    const float* masks = (const float*)d_in[0];
    float* out = (float*)d_out;
    const size_t need = (size_t)BATCH * HH * NSEG * sizeof(unsigned long long); // 2.36 MB
    if (ws_size >= need) {
        unsigned long long* bitsmap = (unsigned long long*)d_ws;
        packbits_kernel<<<dim3(BATCH * HH / 4), 256, 0, stream>>>(masks, bitsmap);
        dim3 grid(HH / TYO, BATCH);    // 16 x 32 = 512 blocks, 2 per CU
        label_gen_fused_bits<<<grid, NT, 0, stream>>>(bitsmap, out);
    } else {
        dim3 grid(HH / TYO, BATCH);
        label_gen_fused<<<grid, NT, 0, stream>>>(masks, out);
    }
}